// Round 1
// baseline (1169.452 us; speedup 1.0000x reference)
//
#include <hip/hip_runtime.h>
#include <math.h>

// Problem constants (fixed by reference): x [4, 64, 64, 128] fp32
constexpr int C     = 128;
constexpr int N     = 4096;   // 64*64 tokens per batch
constexpr int BATCH = 4;

constexpr int BQ   = 32;      // query rows per block
constexpr int BK   = 32;      // key rows per tile
constexpr int STR  = 132;     // padded LDS stride (floats): breaks 128-stride bank aliasing, 16B-aligned
constexpr int PSTR = 36;      // p-matrix padded stride (floats), 16B-aligned rows

// ---------------------------------------------------------------------------
// QKV projection: [16384,128] x [128,128] + bias, three outputs.
// grid (B*N/32, 3), block 256. x-tile staged in LDS; W streamed from L2.
// ---------------------------------------------------------------------------
__global__ __launch_bounds__(256)
void qkv_proj_kernel(const float* __restrict__ x,
                     const float* __restrict__ Wq, const float* __restrict__ bq,
                     const float* __restrict__ Wk, const float* __restrict__ bk,
                     const float* __restrict__ Wv, const float* __restrict__ bv,
                     float* __restrict__ qo, float* __restrict__ ko, float* __restrict__ vo)
{
    __shared__ __align__(16) float xl[32 * STR];
    const float* W; const float* bias; float* out;
    if (blockIdx.y == 0)      { W = Wq; bias = bq; out = qo; }
    else if (blockIdx.y == 1) { W = Wk; bias = bk; out = ko; }
    else                      { W = Wv; bias = bv; out = vo; }

    const int tid  = threadIdx.x;
    const long row0 = (long)blockIdx.x * 32;

    // stage x tile: 32 rows x 32 float4
    #pragma unroll
    for (int t = 0; t < 4; ++t) {
        int idx = t * 256 + tid;             // 0..1023
        int r = idx >> 5, c4 = (idx & 31) * 4;
        *reinterpret_cast<float4*>(&xl[r * STR + c4]) =
            *reinterpret_cast<const float4*>(&x[(row0 + r) * C + c4]);
    }
    __syncthreads();

    const int rg = tid >> 5;       // 0..7  -> rows rg*4 .. rg*4+3
    const int cg = tid & 31;       // 0..31 -> cols cg*4 .. cg*4+3
    const int i0 = rg * 4, c0 = cg * 4;

    float acc[4][4] = {};
    for (int k = 0; k < C; ++k) {
        float4 w = *reinterpret_cast<const float4*>(&W[k * C + c0]);   // L2-resident
        #pragma unroll
        for (int ii = 0; ii < 4; ++ii) {
            float xv = xl[(i0 + ii) * STR + k];
            acc[ii][0] = fmaf(xv, w.x, acc[ii][0]);
            acc[ii][1] = fmaf(xv, w.y, acc[ii][1]);
            acc[ii][2] = fmaf(xv, w.z, acc[ii][2]);
            acc[ii][3] = fmaf(xv, w.w, acc[ii][3]);
        }
    }
    float4 bb = *reinterpret_cast<const float4*>(&bias[c0]);
    #pragma unroll
    for (int ii = 0; ii < 4; ++ii) {
        float4 r;
        r.x = acc[ii][0] + bb.x; r.y = acc[ii][1] + bb.y;
        r.z = acc[ii][2] + bb.z; r.w = acc[ii][3] + bb.w;
        *reinterpret_cast<float4*>(&out[(row0 + i0 + ii) * C + c0]) = r;
    }
}

// ---------------------------------------------------------------------------
// Flash attention (fp32, online softmax), one block per 32 query rows.
// grid (N/BQ, BATCH) = (128, 4), block 256.
// Row ownership: score phase thread (it=tid>>4) owns rows it*2..+1;
// PV phase uses the same mapping, so m/l/alpha live in registers (replicated
// across the 16 lanes of each row-group via shfl_xor reductions).
// ---------------------------------------------------------------------------
__global__ __launch_bounds__(256)
void attn_kernel(const float* __restrict__ x,
                 const float* __restrict__ q,
                 const float* __restrict__ k,
                 const float* __restrict__ v,
                 float* __restrict__ outp)
{
    __shared__ __align__(16) float ql[BQ * STR];    // 16896 B
    __shared__ __align__(16) float kl[BK * STR];    // 16896 B
    __shared__ __align__(16) float vl[BK * STR];    // 16896 B
    __shared__ __align__(16) float pl[BQ * PSTR];   //  4608 B   (total 55296 B -> 2 blocks/CU)

    const int tid = threadIdx.x;
    const int b   = blockIdx.y;
    const int q0  = blockIdx.x * BQ;

    const float* qb = q + ((long)b * N + q0) * C;
    const float* kb = k + (long)b * N * C;
    const float* vb = v + (long)b * N * C;

    // stage q tile: 32 rows x 32 float4
    #pragma unroll
    for (int t = 0; t < 4; ++t) {
        int idx = t * 256 + tid;
        int r = idx >> 5, c4 = (idx & 31) * 4;
        *reinterpret_cast<float4*>(&ql[r * STR + c4]) =
            *reinterpret_cast<const float4*>(&qb[r * C + c4]);
    }

    const int it = tid >> 4;        // 0..15 : rows it*2 .. it*2+1
    const int jt = tid & 15;        // 0..15 : score cols jt*2 .. +1 / PV cols jt*8 .. +7
    const int i0 = it * 2;
    const int j0 = jt * 2;
    const int c0 = jt * 8;

    const float scale = 0.08838834764831845f;   // 1/sqrt(128)

    float m_i[2] = { -1e30f, -1e30f };
    float l_i[2] = { 0.f, 0.f };
    float acc[2][8] = {};                       // rows i0..i0+1, cols c0..c0+7

    for (int kt = 0; kt < N / BK; ++kt) {
        __syncthreads();   // previous iteration's PV reads of v/p complete
        // stage k,v tiles: 32 rows x 32 float4 each
        {
            const float* ks = kb + (long)kt * BK * C;
            const float* vs = vb + (long)kt * BK * C;
            #pragma unroll
            for (int t = 0; t < 4; ++t) {
                int idx = t * 256 + tid;
                int r = idx >> 5, c4 = (idx & 31) * 4;
                *reinterpret_cast<float4*>(&kl[r * STR + c4]) =
                    *reinterpret_cast<const float4*>(&ks[r * C + c4]);
                *reinterpret_cast<float4*>(&vl[r * STR + c4]) =
                    *reinterpret_cast<const float4*>(&vs[r * C + c4]);
            }
        }
        __syncthreads();

        // ---- scores: s[2][2] = q[i0+ii] . k[j0+jj] ----
        float s[2][2] = {};
        for (int c = 0; c < C; c += 4) {
            float4 k0 = *reinterpret_cast<const float4*>(&kl[ j0      * STR + c]);
            float4 k1 = *reinterpret_cast<const float4*>(&kl[(j0 + 1) * STR + c]);
            #pragma unroll
            for (int ii = 0; ii < 2; ++ii) {
                float4 qv = *reinterpret_cast<const float4*>(&ql[(i0 + ii) * STR + c]);
                s[ii][0] += qv.x * k0.x + qv.y * k0.y + qv.z * k0.z + qv.w * k0.w;
                s[ii][1] += qv.x * k1.x + qv.y * k1.y + qv.z * k1.z + qv.w * k1.w;
            }
        }

        // ---- online softmax update (per row, across the 16-lane jt group) ----
        float alpha[2];
        #pragma unroll
        for (int ii = 0; ii < 2; ++ii) {
            float s0 = s[ii][0] * scale, s1 = s[ii][1] * scale;
            float mx = fmaxf(s0, s1);
            #pragma unroll
            for (int off = 1; off < 16; off <<= 1)
                mx = fmaxf(mx, __shfl_xor(mx, off, 64));
            float mnew = fmaxf(m_i[ii], mx);
            float a  = __expf(m_i[ii] - mnew);
            float p0 = __expf(s0 - mnew);
            float p1 = __expf(s1 - mnew);
            float rs = p0 + p1;
            #pragma unroll
            for (int off = 1; off < 16; off <<= 1)
                rs += __shfl_xor(rs, off, 64);
            l_i[ii]  = a * l_i[ii] + rs;
            m_i[ii]  = mnew;
            alpha[ii] = a;
            float2 pw; pw.x = p0; pw.y = p1;
            *reinterpret_cast<float2*>(&pl[(i0 + ii) * PSTR + j0]) = pw;
        }
        __syncthreads();   // p visible

        // ---- PV: acc[ii][cc] += p[i][j] * v[j][c] ----
        #pragma unroll
        for (int ii = 0; ii < 2; ++ii)
            #pragma unroll
            for (int cc = 0; cc < 8; ++cc)
                acc[ii][cc] *= alpha[ii];

        for (int j = 0; j < BK; j += 4) {
            float4 p4[2];
            #pragma unroll
            for (int ii = 0; ii < 2; ++ii)
                p4[ii] = *reinterpret_cast<const float4*>(&pl[(i0 + ii) * PSTR + j]);
            #pragma unroll
            for (int jj = 0; jj < 4; ++jj) {
                float4 va = *reinterpret_cast<const float4*>(&vl[(j + jj) * STR + c0]);
                float4 vb4 = *reinterpret_cast<const float4*>(&vl[(j + jj) * STR + c0 + 4]);
                #pragma unroll
                for (int ii = 0; ii < 2; ++ii) {
                    float p = (jj == 0) ? p4[ii].x : (jj == 1) ? p4[ii].y
                             : (jj == 2) ? p4[ii].z : p4[ii].w;
                    acc[ii][0] = fmaf(p, va.x,  acc[ii][0]);
                    acc[ii][1] = fmaf(p, va.y,  acc[ii][1]);
                    acc[ii][2] = fmaf(p, va.z,  acc[ii][2]);
                    acc[ii][3] = fmaf(p, va.w,  acc[ii][3]);
                    acc[ii][4] = fmaf(p, vb4.x, acc[ii][4]);
                    acc[ii][5] = fmaf(p, vb4.y, acc[ii][5]);
                    acc[ii][6] = fmaf(p, vb4.z, acc[ii][6]);
                    acc[ii][7] = fmaf(p, vb4.w, acc[ii][7]);
                }
            }
        }
    }

    // ---- epilogue: out = x + acc / l ----
    const float* xb = x    + ((long)b * N + q0) * C;
    float*       ob = outp + ((long)b * N + q0) * C;
    #pragma unroll
    for (int ii = 0; ii < 2; ++ii) {
        float inv = 1.0f / l_i[ii];
        int r = i0 + ii;
        #pragma unroll
        for (int cc = 0; cc < 8; cc += 4) {
            float4 xv = *reinterpret_cast<const float4*>(&xb[r * C + c0 + cc]);
            float4 o;
            o.x = xv.x + acc[ii][cc + 0] * inv;
            o.y = xv.y + acc[ii][cc + 1] * inv;
            o.z = xv.z + acc[ii][cc + 2] * inv;
            o.w = xv.w + acc[ii][cc + 3] * inv;
            *reinterpret_cast<float4*>(&ob[r * C + c0 + cc]) = o;
        }
    }
}

// ---------------------------------------------------------------------------
extern "C" void kernel_launch(void* const* d_in, const int* in_sizes, int n_in,
                              void* d_out, int out_size, void* d_ws, size_t ws_size,
                              hipStream_t stream)
{
    const float* x  = (const float*)d_in[0];
    const float* Wq = (const float*)d_in[1];
    const float* bq = (const float*)d_in[2];
    const float* Wk = (const float*)d_in[3];
    const float* bk = (const float*)d_in[4];
    const float* Wv = (const float*)d_in[5];
    const float* bv = (const float*)d_in[6];
    float* out = (float*)d_out;

    // workspace: q,k,v each BATCH*N*C fp32 = 8 MB -> 24 MB total
    float* q = (float*)d_ws;
    float* k = q + (size_t)BATCH * N * C;
    float* v = k + (size_t)BATCH * N * C;

    qkv_proj_kernel<<<dim3(BATCH * N / 32, 3), 256, 0, stream>>>(
        x, Wq, bq, Wk, bk, Wv, bv, q, k, v);
    attn_kernel<<<dim3(N / BQ, BATCH), 256, 0, stream>>>(x, q, k, v, out);
}

// Round 2
// 236.608 us; speedup vs baseline: 4.9426x; 4.9426x over previous
//
#include <hip/hip_runtime.h>
#include <math.h>

// Problem constants: x [4, 64, 64, 128] fp32
constexpr int C     = 128;
constexpr int N     = 4096;
constexpr int BATCH = 4;

constexpr int BQ = 32;        // query rows per block
constexpr int BK = 64;        // key rows per tile

// LDS strides in bf16 elements. All chosen so row stride is a multiple of
// 16 B (b128-aligned) and ≡ 4 mod 32 banks (breaks power-of-2 aliasing).
constexpr int KSTR = 136;     // q/k tiles: 128 + 8
constexpr int VSTR = 72;      // v^T tile : 64 + 8
constexpr int PSTR = 72;      // P tile   : 64 + 8

constexpr float SCALE = 0.08838834764831845f;   // 1/sqrt(128)

typedef __attribute__((ext_vector_type(8))) short          bf16x8;
typedef __attribute__((ext_vector_type(4))) float          f32x4;
typedef __attribute__((ext_vector_type(4))) unsigned short us4;

__device__ inline unsigned short f2bf(float f) {   // RNE float->bf16
    unsigned int u = __float_as_uint(f);
    return (unsigned short)((u + 0x7FFFu + ((u >> 16) & 1u)) >> 16);
}

// ---------------------------------------------------------------------------
// QKV projection: [16384,128] x [128,128] + bias.
// Outputs bf16: q (pre-scaled by 1/sqrt(C)) [b*n][c], k [b*n][c], vt [b][c][n].
// grid (B*N/32, 3), block 256.
// ---------------------------------------------------------------------------
__global__ __launch_bounds__(256)
void qkv_proj_kernel(const float* __restrict__ x,
                     const float* __restrict__ Wq, const float* __restrict__ bq,
                     const float* __restrict__ Wk, const float* __restrict__ bk,
                     const float* __restrict__ Wv, const float* __restrict__ bv,
                     unsigned short* __restrict__ qo,
                     unsigned short* __restrict__ ko,
                     unsigned short* __restrict__ vt)
{
    constexpr int XSTR = 132;
    __shared__ __align__(16) float xl[32 * XSTR];

    const float* W; const float* bias;
    if (blockIdx.y == 0)      { W = Wq; bias = bq; }
    else if (blockIdx.y == 1) { W = Wk; bias = bk; }
    else                      { W = Wv; bias = bv; }

    const int tid   = threadIdx.x;
    const long row0 = (long)blockIdx.x * 32;

    #pragma unroll
    for (int t = 0; t < 4; ++t) {
        int idx = t * 256 + tid;
        int r = idx >> 5, c4 = (idx & 31) * 4;
        *reinterpret_cast<float4*>(&xl[r * XSTR + c4]) =
            *reinterpret_cast<const float4*>(&x[(row0 + r) * C + c4]);
    }
    __syncthreads();

    const int rg = tid >> 5;
    const int cg = tid & 31;
    const int i0 = rg * 4, c0 = cg * 4;

    float acc[4][4] = {};
    for (int k = 0; k < C; ++k) {
        float4 w = *reinterpret_cast<const float4*>(&W[k * C + c0]);
        #pragma unroll
        for (int ii = 0; ii < 4; ++ii) {
            float xv = xl[(i0 + ii) * XSTR + k];
            acc[ii][0] = fmaf(xv, w.x, acc[ii][0]);
            acc[ii][1] = fmaf(xv, w.y, acc[ii][1]);
            acc[ii][2] = fmaf(xv, w.z, acc[ii][2]);
            acc[ii][3] = fmaf(xv, w.w, acc[ii][3]);
        }
    }
    float4 bb = *reinterpret_cast<const float4*>(&bias[c0]);
    float bbv[4] = { bb.x, bb.y, bb.z, bb.w };

    if (blockIdx.y == 2) {
        // v: store transposed vt[b][c][n], 4 consecutive n per store
        const int  bidx = (int)(row0 >> 12);
        const int  n0   = (int)(row0 & (N - 1)) + i0;
        unsigned short* vb = vt + (long)bidx * C * N;
        #pragma unroll
        for (int cc = 0; cc < 4; ++cc) {
            us4 w;
            w[0] = f2bf(acc[0][cc] + bbv[cc]);
            w[1] = f2bf(acc[1][cc] + bbv[cc]);
            w[2] = f2bf(acc[2][cc] + bbv[cc]);
            w[3] = f2bf(acc[3][cc] + bbv[cc]);
            *reinterpret_cast<us4*>(&vb[(long)(c0 + cc) * N + n0]) = w;
        }
    } else {
        const float s = (blockIdx.y == 0) ? SCALE : 1.0f;
        unsigned short* out = (blockIdx.y == 0) ? qo : ko;
        #pragma unroll
        for (int ii = 0; ii < 4; ++ii) {
            us4 w;
            #pragma unroll
            for (int cc = 0; cc < 4; ++cc)
                w[cc] = f2bf((acc[ii][cc] + bbv[cc]) * s);
            *reinterpret_cast<us4*>(&out[(row0 + i0 + ii) * C + c0]) = w;
        }
    }
}

// ---------------------------------------------------------------------------
// MFMA flash attention. grid (N/BQ, BATCH) = (128,4), block 256 (4 waves).
// wave = (mi = wave&1 -> 16-row M-tile, kh = wave>>1 -> key-half / chan-half).
// Fragment layouts (gfx950 16x16x32 bf16, HW-verified m89/m91/m97/m120):
//   A: lane holds A[m=lane&15][k=quad*8+j]   (8 contiguous bf16 of a row)
//   B: lane holds B^T row: Bt[n=lane&15][k=quad*8+j]
//   C/D: col=lane&15, row=quad*4+reg
// ---------------------------------------------------------------------------
__global__ __launch_bounds__(256)
void attn_kernel(const float* __restrict__ x,
                 const unsigned short* __restrict__ q,
                 const unsigned short* __restrict__ k,
                 const unsigned short* __restrict__ vt,
                 float* __restrict__ outp)
{
    __shared__ __align__(16) unsigned short ql[BQ  * KSTR];   //  8704 B
    __shared__ __align__(16) unsigned short kl[BK  * KSTR];   // 17408 B
    __shared__ __align__(16) unsigned short vl[C   * VSTR];   // 18432 B
    __shared__ __align__(16) unsigned short pl[BQ  * PSTR];   //  4608 B
    __shared__ float mbuf[2][BQ];
    __shared__ float sbuf[2][BQ];

    const int tid  = threadIdx.x;
    const int wave = tid >> 6;
    const int lane = tid & 63;
    const int lo   = lane & 15;
    const int quad = lane >> 4;
    const int mi   = wave & 1;    // M-tile (rows mi*16..+15)
    const int kh   = wave >> 1;   // key half (S) / channel half (PV)

    const int b  = blockIdx.y;
    const int q0 = blockIdx.x * BQ;

    const unsigned short* qb  = q  + ((long)b * N + q0) * C;
    const unsigned short* kb  = k  + (long)b * N * C;
    const unsigned short* vtb = vt + (long)b * C * N;

    // ---- stage Q (once) ----
    #pragma unroll
    for (int t = 0; t < 2; ++t) {
        int idx = t * 256 + tid;          // 0..511
        int r = idx >> 4, c16 = idx & 15;
        *reinterpret_cast<uint4*>(&ql[r * KSTR + c16 * 8]) =
            *reinterpret_cast<const uint4*>(&qb[r * C + c16 * 8]);
    }
    __syncthreads();

    // preload Q fragments (row mi*16+lo, 4 k-steps)
    bf16x8 qf[4];
    #pragma unroll
    for (int ks = 0; ks < 4; ++ks)
        qf[ks] = *reinterpret_cast<const bf16x8*>(
            &ql[(mi * 16 + lo) * KSTR + ks * 32 + quad * 8]);

    float m_i[4] = { -1e30f, -1e30f, -1e30f, -1e30f };
    float l_i[4] = { 0.f, 0.f, 0.f, 0.f };
    f32x4 oacc[4] = {};   // channels kh*64 + nt2*16 + lo, rows mi*16+quad*4+r

    for (int kt = 0; kt < N / BK; ++kt) {
        __syncthreads();   // all waves done reading kl/vl/pl of prev iter

        // ---- stage K tile (64x128) and Vt tile (128x64) ----
        {
            const unsigned short* ks_ = kb  + (long)(kt * BK) * C;
            const unsigned short* vs_ = vtb + kt * BK;
            #pragma unroll
            for (int t = 0; t < 4; ++t) {
                int idx = t * 256 + tid;              // 0..1023
                int r = idx >> 4, c16 = idx & 15;
                *reinterpret_cast<uint4*>(&kl[r * KSTR + c16 * 8]) =
                    *reinterpret_cast<const uint4*>(&ks_[r * C + c16 * 8]);
                int rv = idx >> 3, j8 = idx & 7;
                *reinterpret_cast<uint4*>(&vl[rv * VSTR + j8 * 8]) =
                    *reinterpret_cast<const uint4*>(&vs_[(long)rv * N + j8 * 8]);
            }
        }
        __syncthreads();

        // ---- S = Q . K^T  (wave: 16 rows x 32 key cols) ----
        f32x4 sacc[2] = {};
        #pragma unroll
        for (int ks = 0; ks < 4; ++ks) {
            #pragma unroll
            for (int nt = 0; nt < 2; ++nt) {
                bf16x8 bf = *reinterpret_cast<const bf16x8*>(
                    &kl[(kh * 32 + nt * 16 + lo) * KSTR + ks * 32 + quad * 8]);
                sacc[nt] = __builtin_amdgcn_mfma_f32_16x16x32_bf16(
                    qf[ks], bf, sacc[nt], 0, 0, 0);
            }
        }

        // ---- partial row max (this wave's 32 key cols) ----
        float pm[4];
        #pragma unroll
        for (int r = 0; r < 4; ++r) {
            float v = fmaxf(sacc[0][r], sacc[1][r]);
            #pragma unroll
            for (int off = 1; off < 16; off <<= 1)
                v = fmaxf(v, __shfl_xor(v, off, 64));
            pm[r] = v;
        }
        if (lo == 0) {
            #pragma unroll
            for (int r = 0; r < 4; ++r)
                mbuf[kh][mi * 16 + quad * 4 + r] = pm[r];
        }
        __syncthreads();

        // ---- combine max, compute p, partial sums, write P ----
        float alpha[4], rs[4];
        #pragma unroll
        for (int r = 0; r < 4; ++r) {
            int rowidx = mi * 16 + quad * 4 + r;
            float mn = fmaxf(m_i[r], fmaxf(pm[r], mbuf[1 - kh][rowidx]));
            alpha[r] = __expf(m_i[r] - mn);
            m_i[r]   = mn;
            float p0 = __expf(sacc[0][r] - mn);
            float p1 = __expf(sacc[1][r] - mn);
            float v  = p0 + p1;
            pl[rowidx * PSTR + kh * 32 + lo]      = f2bf(p0);
            pl[rowidx * PSTR + kh * 32 + 16 + lo] = f2bf(p1);
            #pragma unroll
            for (int off = 1; off < 16; off <<= 1)
                v += __shfl_xor(v, off, 64);
            rs[r] = v;
        }
        if (lo == 0) {
            #pragma unroll
            for (int r = 0; r < 4; ++r)
                sbuf[kh][mi * 16 + quad * 4 + r] = rs[r];
        }
        __syncthreads();

        #pragma unroll
        for (int r = 0; r < 4; ++r) {
            int rowidx = mi * 16 + quad * 4 + r;
            l_i[r] = alpha[r] * l_i[r] + rs[r] + sbuf[1 - kh][rowidx];
        }

        // ---- O rescale + PV (wave: 16 rows x 64 channels at kh*64) ----
        #pragma unroll
        for (int nt2 = 0; nt2 < 4; ++nt2)
            #pragma unroll
            for (int r = 0; r < 4; ++r)
                oacc[nt2][r] *= alpha[r];

        #pragma unroll
        for (int ks2 = 0; ks2 < 2; ++ks2) {
            bf16x8 af = *reinterpret_cast<const bf16x8*>(
                &pl[(mi * 16 + lo) * PSTR + ks2 * 32 + quad * 8]);
            #pragma unroll
            for (int nt2 = 0; nt2 < 4; ++nt2) {
                bf16x8 bv = *reinterpret_cast<const bf16x8*>(
                    &vl[(kh * 64 + nt2 * 16 + lo) * VSTR + ks2 * 32 + quad * 8]);
                oacc[nt2] = __builtin_amdgcn_mfma_f32_16x16x32_bf16(
                    af, bv, oacc[nt2], 0, 0, 0);
            }
        }
    }

    // ---- epilogue: out = x + O / l ----
    #pragma unroll
    for (int r = 0; r < 4; ++r) {
        float inv = 1.0f / l_i[r];
        long grow = (long)b * N + q0 + mi * 16 + quad * 4 + r;
        #pragma unroll
        for (int nt2 = 0; nt2 < 4; ++nt2) {
            int col = kh * 64 + nt2 * 16 + lo;
            outp[grow * C + col] = x[grow * C + col] + oacc[nt2][r] * inv;
        }
    }
}

// ---------------------------------------------------------------------------
extern "C" void kernel_launch(void* const* d_in, const int* in_sizes, int n_in,
                              void* d_out, int out_size, void* d_ws, size_t ws_size,
                              hipStream_t stream)
{
    const float* x  = (const float*)d_in[0];
    const float* Wq = (const float*)d_in[1];
    const float* bq = (const float*)d_in[2];
    const float* Wk = (const float*)d_in[3];
    const float* bk = (const float*)d_in[4];
    const float* Wv = (const float*)d_in[5];
    const float* bv = (const float*)d_in[6];
    float* out = (float*)d_out;

    // workspace: q, k, vt each B*N*C bf16 = 4 MB
    unsigned short* q  = (unsigned short*)d_ws;
    unsigned short* k  = q  + (size_t)BATCH * N * C;
    unsigned short* vt = k  + (size_t)BATCH * N * C;

    qkv_proj_kernel<<<dim3(BATCH * N / 32, 3), 256, 0, stream>>>(
        x, Wq, bq, Wk, bk, Wv, bv, q, k, vt);
    attn_kernel<<<dim3(N / BQ, BATCH), 256, 0, stream>>>(x, q, k, vt, out);
}